// Round 7
// baseline (253.249 us; speedup 1.0000x reference)
//
#include <hip/hip_runtime.h>
#include <hip/hip_cooperative_groups.h>
#include <math.h>

namespace cg = cooperative_groups;

#define N_NODES 8192
#define F_IN    256
#define F_OUT   128
#define DEG     32
#define ALPHA   0.2f
#define GBLK    512           // cooperative grid: 2 blocks/CU co-resident
#define RPB     16            // rows per block

typedef __attribute__((ext_vector_type(8))) short short8;   // 8 bf16 = 4 VGPR
typedef __attribute__((ext_vector_type(4))) float floatx4;  // MFMA acc

__device__ __forceinline__ unsigned short f2bf(float x) {   // RNE f32->bf16
    unsigned u = __float_as_uint(x);
    return (unsigned short)((u + 0x7fffu + ((u >> 16) & 1u)) >> 16);
}

// ---- Kernel P: prep = pack W B-frags (blocks 0..63) + wa=W@a (blocks 64..67)
// B-frag layout (v5/v6-verified): frag f = kt*8 + gnt; lane holds
// B[k = kt*32 + quad*8 + j][n = gnt*16 + (lane&15)], j=0..7.
__global__ __launch_bounds__(64) void prep_kernel(
        const float* __restrict__ W, const float* __restrict__ a,
        unsigned short* __restrict__ Wtf,
        float* __restrict__ wa1, float* __restrict__ wa2) {
    const int bid = blockIdx.x;
    const int tid = threadIdx.x;
    if (bid < 64) {
        const int quad = tid >> 4;
        const int l15  = tid & 15;
        const int kt   = bid >> 3;
        const int gnt  = bid & 7;
        const int n    = gnt * 16 + l15;
        const int kb   = kt * 32 + quad * 8;
        unsigned short s[8];
        #pragma unroll
        for (int j = 0; j < 8; ++j)
            s[j] = f2bf(W[(size_t)(kb + j) * F_OUT + n]);
        uint4 p;
        p.x = (unsigned)s[0] | ((unsigned)s[1] << 16);
        p.y = (unsigned)s[2] | ((unsigned)s[3] << 16);
        p.z = (unsigned)s[4] | ((unsigned)s[5] << 16);
        p.w = (unsigned)s[6] | ((unsigned)s[7] << 16);
        ((uint4*)Wtf)[(size_t)bid * 64 + tid] = p;
    } else {
        const int k = (bid - 64) * 64 + tid;          // 0..255
        const float* wr = W + (size_t)k * F_OUT;
        float s1 = 0.f, s2 = 0.f;
        #pragma unroll 4
        for (int n = 0; n < F_OUT; n += 4) {
            float4 wv = *(const float4*)(wr + n);
            float4 a1 = *(const float4*)(a + n);
            float4 a2 = *(const float4*)(a + F_OUT + n);
            s1 = fmaf(wv.x,a1.x, fmaf(wv.y,a1.y, fmaf(wv.z,a1.z, fmaf(wv.w,a1.w, s1))));
            s2 = fmaf(wv.x,a2.x, fmaf(wv.y,a2.y, fmaf(wv.z,a2.z, fmaf(wv.w,a2.w, s2))));
        }
        wa1[k] = s1;
        wa2[k] = s2;
    }
}

// ---- Cooperative fused kernel: GEMM phase -> grid.sync -> attn phase --------
__global__ __launch_bounds__(256) void fused_coop(
        const float* __restrict__ h,
        const unsigned short* __restrict__ Wtf,
        const float* __restrict__ wa1,
        const float* __restrict__ wa2,
        const int*   __restrict__ nbr,
        unsigned short* __restrict__ hWb,   // [8192][128] bf16
        float* __restrict__ h1,
        float* __restrict__ h2,
        float* __restrict__ out) {
    cg::grid_group grid = cg::this_grid();

    const int tid  = threadIdx.x;
    const int wave = tid >> 6;             // 0..3
    const int lane = tid & 63;
    const int quad = lane >> 4;
    const int l15  = lane & 15;
    const int row0 = blockIdx.x * RPB;

    // ================= GEMM phase (v6-verified) =================
    {
        const float* hrow = h + (size_t)(row0 + l15) * F_IN + quad * 8;
        const short8* Wf  = (const short8*)Wtf;

        floatx4 acc[2] = {{0.f,0.f,0.f,0.f},{0.f,0.f,0.f,0.f}};
        float s1 = 0.f, s2 = 0.f;

        #pragma unroll
        for (int kt = 0; kt < 8; ++kt) {
            float4 v0 = *(const float4*)(hrow + kt * 32);
            float4 v1 = *(const float4*)(hrow + kt * 32 + 4);
            short8 af;
            af[0] = (short)f2bf(v0.x); af[1] = (short)f2bf(v0.y);
            af[2] = (short)f2bf(v0.z); af[3] = (short)f2bf(v0.w);
            af[4] = (short)f2bf(v1.x); af[5] = (short)f2bf(v1.y);
            af[6] = (short)f2bf(v1.z); af[7] = (short)f2bf(v1.w);

            #pragma unroll
            for (int nt = 0; nt < 2; ++nt) {
                short8 bf = Wf[(size_t)(kt * 8 + wave * 2 + nt) * 64 + lane];
                acc[nt] = __builtin_amdgcn_mfma_f32_16x16x32_bf16(af, bf, acc[nt], 0, 0, 0);
            }

            if (wave == 0) {               // f32 score path: s += h · wa
                const int kb = kt * 32 + quad * 8;
                float4 u0 = *(const float4*)(wa1 + kb);
                float4 u1 = *(const float4*)(wa1 + kb + 4);
                float4 t0 = *(const float4*)(wa2 + kb);
                float4 t1 = *(const float4*)(wa2 + kb + 4);
                s1 = fmaf(v0.x,u0.x, fmaf(v0.y,u0.y, fmaf(v0.z,u0.z, fmaf(v0.w,u0.w, s1))));
                s1 = fmaf(v1.x,u1.x, fmaf(v1.y,u1.y, fmaf(v1.z,u1.z, fmaf(v1.w,u1.w, s1))));
                s2 = fmaf(v0.x,t0.x, fmaf(v0.y,t0.y, fmaf(v0.z,t0.z, fmaf(v0.w,t0.w, s2))));
                s2 = fmaf(v1.x,t1.x, fmaf(v1.y,t1.y, fmaf(v1.z,t1.z, fmaf(v1.w,t1.w, s2))));
            }
        }

        // store hW bf16: C/D layout col=lane&15, row=quad*4+reg
        #pragma unroll
        for (int nt = 0; nt < 2; ++nt) {
            const int col = wave * 32 + nt * 16 + l15;
            #pragma unroll
            for (int reg = 0; reg < 4; ++reg) {
                const int row = row0 + quad * 4 + reg;
                hWb[(size_t)row * F_OUT + col] = f2bf(acc[nt][reg]);
            }
        }

        if (wave == 0) {
            s1 += __shfl_xor(s1, 16); s1 += __shfl_xor(s1, 32);
            s2 += __shfl_xor(s2, 16); s2 += __shfl_xor(s2, 32);
            if (lane < 16) {
                h1[row0 + l15] = s1;
                h2[row0 + l15] = s2;
            }
        }
    }

    __threadfence();          // release our hWb/h1/h2 writes to device scope
    grid.sync();              // grid-wide barrier + memory coherence

    // ================= attn phase (v6-verified body) =================
    const unsigned int* hWp = (const unsigned int*)hWb;
    #pragma unroll
    for (int r = 0; r < 4; ++r) {
        const int row = row0 + wave * 4 + r;

        int col = -1;
        if (lane < DEG)       col = nbr[(size_t)row * DEG + lane];
        else if (lane == DEG) col = row;

        // dedup + multiplicity over the 33 candidate slots
        int cnt = 0;
        int firstq = lane;
        #pragma unroll
        for (int q = 0; q <= DEG; ++q) {
            int cq = __shfl(col, q);
            bool same = (cq == col);
            if (same && q < DEG)    cnt++;
            if (same && q < firstq) firstq = q;
        }
        const bool active = (lane <= DEG) && (col >= 0) && (firstq == lane);

        float mask_val = (float)cnt * (1.0f / 64.0f) + ((col == row) ? 0.5f : 0.0f);

        const float h1row = h1[row];
        float h2c = active ? h2[col] : 0.f;
        float s = mask_val * (h1row + h2c);
        float e = (s > 0.f) ? s : ALPHA * s;            // LeakyReLU
        bool valid = active && (e != 0.0f);             // e==0 -> NEG_INF in ref

        float ev = valid ? e : -INFINITY;
        #pragma unroll
        for (int off = 32; off > 0; off >>= 1)
            ev = fmaxf(ev, __shfl_xor(ev, off));
        float w = valid ? __expf(e - ev) : 0.f;
        float denom = w;
        #pragma unroll
        for (int off = 32; off > 0; off >>= 1)
            denom += __shfl_xor(denom, off);
        float att = w / denom;

        // aggregate: 4 B bf16x2 gathers (256 B per candidate row)
        float acc0 = 0.f, acc1 = 0.f;
        #pragma unroll
        for (int q = 0; q <= DEG; ++q) {
            float aq = __shfl(att, q);
            int   cq = __shfl(col, q);
            if (aq > 0.f) {                              // wave-uniform branch
                unsigned v = hWp[(size_t)cq * (F_OUT / 2) + lane];
                float lo = __uint_as_float(v << 16);
                float hi = __uint_as_float(v & 0xffff0000u);
                acc0 = fmaf(aq, lo, acc0);
                acc1 = fmaf(aq, hi, acc1);
            }
        }

        float o0 = (acc0 > 0.f) ? acc0 : expm1f(acc0);
        float o1 = (acc1 > 0.f) ? acc1 : expm1f(acc1);
        *(float2*)(out + (size_t)row * F_OUT + 2 * lane) = make_float2(o0, o1);
    }
}

// -----------------------------------------------------------------------------
extern "C" void kernel_launch(void* const* d_in, const int* in_sizes, int n_in,
                              void* d_out, int out_size, void* d_ws, size_t ws_size,
                              hipStream_t stream) {
    const float* h   = (const float*)d_in[0];   // [8192, 256]
    const float* W   = (const float*)d_in[1];   // [256, 128]
    const float* a   = (const float*)d_in[2];   // [256, 1]
    const int*   nbr = (const int*)  d_in[3];   // [8192, 32]
    float* out = (float*)d_out;                 // [8192, 128]

    // ws: hWb bf16 (2 MB) | h1 (32 KB) | h2 (32 KB) | Wtf (64 KB) | wa1 | wa2
    unsigned short* hWb = (unsigned short*)d_ws;
    float* h1 = (float*)(hWb + (size_t)N_NODES * F_OUT);
    float* h2 = h1 + N_NODES;
    unsigned short* Wtf = (unsigned short*)(h2 + N_NODES);
    float* wa1 = (float*)(Wtf + (size_t)F_IN * F_OUT);
    float* wa2 = wa1 + F_IN;

    prep_kernel<<<68, 64, 0, stream>>>(W, a, Wtf, wa1, wa2);

    void* kargs[] = {(void*)&h, (void*)&Wtf, (void*)&wa1, (void*)&wa2,
                     (void*)&nbr, (void*)&hWb, (void*)&h1, (void*)&h2,
                     (void*)&out};
    hipLaunchCooperativeKernel((void*)fused_coop, dim3(GBLK), dim3(256),
                               kargs, 0, stream);
}

// Round 8
// 85.251 us; speedup vs baseline: 2.9706x; 2.9706x over previous
//
#include <hip/hip_runtime.h>
#include <math.h>

#define N_NODES 8192
#define F_IN    256
#define F_OUT   128
#define DEG     32
#define ALPHA   0.2f

typedef __attribute__((ext_vector_type(8))) short short8;   // 8 bf16 = 4 VGPR
typedef __attribute__((ext_vector_type(4))) float floatx4;  // MFMA acc

__device__ __forceinline__ unsigned short f2bf(float x) {   // RNE f32->bf16
    unsigned u = __float_as_uint(x);
    return (unsigned short)((u + 0x7fffu + ((u >> 16) & 1u)) >> 16);
}

// ---- Kernel P: prep = pack W B-frags (blocks 0..63) + wa=W@a (blocks 64..67)
// B-frag layout (v5/v6-verified): frag f = kt*8 + gnt; lane holds
// B[k = kt*32 + quad*8 + j][n = gnt*16 + (lane&15)], j=0..7.
__global__ __launch_bounds__(64) void prep_kernel(
        const float* __restrict__ W, const float* __restrict__ a,
        unsigned short* __restrict__ Wtf,
        float* __restrict__ wa1, float* __restrict__ wa2) {
    const int bid = blockIdx.x;
    const int tid = threadIdx.x;
    if (bid < 64) {
        const int quad = tid >> 4;
        const int l15  = tid & 15;
        const int kt   = bid >> 3;
        const int gnt  = bid & 7;
        const int n    = gnt * 16 + l15;
        const int kb   = kt * 32 + quad * 8;
        unsigned short s[8];
        #pragma unroll
        for (int j = 0; j < 8; ++j)
            s[j] = f2bf(W[(size_t)(kb + j) * F_OUT + n]);
        uint4 p;
        p.x = (unsigned)s[0] | ((unsigned)s[1] << 16);
        p.y = (unsigned)s[2] | ((unsigned)s[3] << 16);
        p.z = (unsigned)s[4] | ((unsigned)s[5] << 16);
        p.w = (unsigned)s[6] | ((unsigned)s[7] << 16);
        ((uint4*)Wtf)[(size_t)bid * 64 + tid] = p;
    } else {
        const int k = (bid - 64) * 64 + tid;          // 0..255
        const float* wr = W + (size_t)k * F_OUT;
        float s1 = 0.f, s2 = 0.f;
        #pragma unroll 4
        for (int n = 0; n < F_OUT; n += 4) {
            float4 wv = *(const float4*)(wr + n);
            float4 a1 = *(const float4*)(a + n);
            float4 a2 = *(const float4*)(a + F_OUT + n);
            s1 = fmaf(wv.x,a1.x, fmaf(wv.y,a1.y, fmaf(wv.z,a1.z, fmaf(wv.w,a1.w, s1))));
            s2 = fmaf(wv.x,a2.x, fmaf(wv.y,a2.y, fmaf(wv.z,a2.z, fmaf(wv.w,a2.w, s2))));
        }
        wa1[k] = s1;
        wa2[k] = s2;
    }
}

// ---- Kernel A: hW(bf16) = h @ W via MFMA; h1/h2 from f32 h · (W@a) ----------
// (v6-verified, unchanged) 512 blocks x 256 thr. Block: 16 rows x 128 cols.
__global__ __launch_bounds__(256) void gemm_mfma_v6(
        const float* __restrict__ h,
        const unsigned short* __restrict__ Wtf,
        const float* __restrict__ wa1,
        const float* __restrict__ wa2,
        unsigned short* __restrict__ hWb,   // [8192][128] bf16
        float* __restrict__ h1,
        float* __restrict__ h2) {
    const int tid  = threadIdx.x;
    const int wave = tid >> 6;             // 0..3 = col quarter
    const int lane = tid & 63;
    const int quad = lane >> 4;
    const int l15  = lane & 15;
    const int row0 = blockIdx.x * 16;

    const float* hrow = h + (size_t)(row0 + l15) * F_IN + quad * 8;
    const short8* Wf  = (const short8*)Wtf;

    floatx4 acc[2] = {{0.f,0.f,0.f,0.f},{0.f,0.f,0.f,0.f}};
    float s1 = 0.f, s2 = 0.f;

    #pragma unroll
    for (int kt = 0; kt < 8; ++kt) {
        float4 v0 = *(const float4*)(hrow + kt * 32);
        float4 v1 = *(const float4*)(hrow + kt * 32 + 4);
        short8 af;
        af[0] = (short)f2bf(v0.x); af[1] = (short)f2bf(v0.y);
        af[2] = (short)f2bf(v0.z); af[3] = (short)f2bf(v0.w);
        af[4] = (short)f2bf(v1.x); af[5] = (short)f2bf(v1.y);
        af[6] = (short)f2bf(v1.z); af[7] = (short)f2bf(v1.w);

        #pragma unroll
        for (int nt = 0; nt < 2; ++nt) {
            short8 bf = Wf[(size_t)(kt * 8 + wave * 2 + nt) * 64 + lane];
            acc[nt] = __builtin_amdgcn_mfma_f32_16x16x32_bf16(af, bf, acc[nt], 0, 0, 0);
        }

        if (wave == 0) {                   // f32 score path: s += h · wa
            const int kb = kt * 32 + quad * 8;
            float4 u0 = *(const float4*)(wa1 + kb);
            float4 u1 = *(const float4*)(wa1 + kb + 4);
            float4 t0 = *(const float4*)(wa2 + kb);
            float4 t1 = *(const float4*)(wa2 + kb + 4);
            s1 = fmaf(v0.x,u0.x, fmaf(v0.y,u0.y, fmaf(v0.z,u0.z, fmaf(v0.w,u0.w, s1))));
            s1 = fmaf(v1.x,u1.x, fmaf(v1.y,u1.y, fmaf(v1.z,u1.z, fmaf(v1.w,u1.w, s1))));
            s2 = fmaf(v0.x,t0.x, fmaf(v0.y,t0.y, fmaf(v0.z,t0.z, fmaf(v0.w,t0.w, s2))));
            s2 = fmaf(v1.x,t1.x, fmaf(v1.y,t1.y, fmaf(v1.z,t1.z, fmaf(v1.w,t1.w, s2))));
        }
    }

    // store hW bf16: C/D layout col=lane&15, row=quad*4+reg
    #pragma unroll
    for (int nt = 0; nt < 2; ++nt) {
        const int col = wave * 32 + nt * 16 + l15;
        #pragma unroll
        for (int reg = 0; reg < 4; ++reg) {
            const int row = row0 + quad * 4 + reg;
            hWb[(size_t)row * F_OUT + col] = f2bf(acc[nt][reg]);
        }
    }

    if (wave == 0) {
        s1 += __shfl_xor(s1, 16); s1 += __shfl_xor(s1, 32);
        s2 += __shfl_xor(s2, 16); s2 += __shfl_xor(s2, 32);
        if (lane < 16) {
            h1[row0 + l15] = s1;
            h2[row0 + l15] = s2;
        }
    }
}

// ---- Kernel C v8: sparse softmax + WIDE bf16 aggregation + ELU --------------
// one wave per row. Softmax part identical to v6. Gather part: 4 candidates
// per iteration; lane-group grp=lane>>4 handles candidate q=it*4+grp, each
// lane loads 16 B (8 bf16 cols) -> full 1 KiB wave transactions; final
// shfl_xor(16/32) folds the 4 groups.
__global__ __launch_bounds__(256) void attn_kernel_v8(
        const unsigned short* __restrict__ hWb,    // [8192][128] bf16
        const float* __restrict__ h1,
        const float* __restrict__ h2,
        const int*   __restrict__ nbr,
        float* __restrict__ out) {
    const int wave = threadIdx.x >> 6;
    const int lane = threadIdx.x & 63;
    const int row  = blockIdx.x * 4 + wave;
    const int grp  = lane >> 4;
    const int l15  = lane & 15;

    int col = -1;
    if (lane < DEG)       col = nbr[(size_t)row * DEG + lane];
    else if (lane == DEG) col = row;

    // dedup + multiplicity over the 33 candidate slots (scatter-add semantics)
    int cnt = 0;
    int firstq = lane;
    #pragma unroll
    for (int q = 0; q <= DEG; ++q) {
        int cq = __shfl(col, q);
        bool same = (cq == col);
        if (same && q < DEG)    cnt++;
        if (same && q < firstq) firstq = q;
    }
    const bool active = (lane <= DEG) && (col >= 0) && (firstq == lane);

    float mask_val = (float)cnt * (1.0f / 64.0f) + ((col == row) ? 0.5f : 0.0f);

    const float h1row = h1[row];
    float h2c = active ? h2[col] : 0.f;
    float s = mask_val * (h1row + h2c);
    float e = (s > 0.f) ? s : ALPHA * s;            // LeakyReLU
    bool valid = active && (e != 0.0f);             // e==0 -> NEG_INF in ref

    float ev = valid ? e : -INFINITY;
    #pragma unroll
    for (int off = 32; off > 0; off >>= 1)
        ev = fmaxf(ev, __shfl_xor(ev, off));
    float w = valid ? __expf(e - ev) : 0.f;
    float denom = w;
    #pragma unroll
    for (int off = 32; off > 0; off >>= 1)
        denom += __shfl_xor(denom, off);
    float att = w / denom;                          // 0 for invalid lanes

    // ---- wide gather: candidate q = it*4 + grp; lane covers cols l15*8..+8 --
    float acc[8] = {0.f,0.f,0.f,0.f,0.f,0.f,0.f,0.f};
    #pragma unroll
    for (int it = 0; it < 9; ++it) {
        const int q  = it * 4 + grp;                // 0..35 (33..35 -> att 0)
        float aq = __shfl(att, q);                  // per-lane idx -> bpermute
        int   cq = __shfl(col, q);
        if (aq > 0.f) {
            uint4 p = ((const uint4*)(hWb + (size_t)cq * F_OUT))[l15];
            acc[0] = fmaf(aq, __uint_as_float(p.x << 16),          acc[0]);
            acc[1] = fmaf(aq, __uint_as_float(p.x & 0xffff0000u),  acc[1]);
            acc[2] = fmaf(aq, __uint_as_float(p.y << 16),          acc[2]);
            acc[3] = fmaf(aq, __uint_as_float(p.y & 0xffff0000u),  acc[3]);
            acc[4] = fmaf(aq, __uint_as_float(p.z << 16),          acc[4]);
            acc[5] = fmaf(aq, __uint_as_float(p.z & 0xffff0000u),  acc[5]);
            acc[6] = fmaf(aq, __uint_as_float(p.w << 16),          acc[6]);
            acc[7] = fmaf(aq, __uint_as_float(p.w & 0xffff0000u),  acc[7]);
        }
    }
    // fold the 4 lane-groups
    #pragma unroll
    for (int j = 0; j < 8; ++j) {
        acc[j] += __shfl_xor(acc[j], 16);
        acc[j] += __shfl_xor(acc[j], 32);
    }

    if (grp == 0) {                                 // lanes 0..15 store 32 B each
        float4 o0, o1;
        o0.x = (acc[0] > 0.f) ? acc[0] : expm1f(acc[0]);
        o0.y = (acc[1] > 0.f) ? acc[1] : expm1f(acc[1]);
        o0.z = (acc[2] > 0.f) ? acc[2] : expm1f(acc[2]);
        o0.w = (acc[3] > 0.f) ? acc[3] : expm1f(acc[3]);
        o1.x = (acc[4] > 0.f) ? acc[4] : expm1f(acc[4]);
        o1.y = (acc[5] > 0.f) ? acc[5] : expm1f(acc[5]);
        o1.z = (acc[6] > 0.f) ? acc[6] : expm1f(acc[6]);
        o1.w = (acc[7] > 0.f) ? acc[7] : expm1f(acc[7]);
        float* orow = out + (size_t)row * F_OUT + l15 * 8;
        *(float4*)(orow)     = o0;
        *(float4*)(orow + 4) = o1;
    }
}

// -----------------------------------------------------------------------------
extern "C" void kernel_launch(void* const* d_in, const int* in_sizes, int n_in,
                              void* d_out, int out_size, void* d_ws, size_t ws_size,
                              hipStream_t stream) {
    const float* h   = (const float*)d_in[0];   // [8192, 256]
    const float* W   = (const float*)d_in[1];   // [256, 128]
    const float* a   = (const float*)d_in[2];   // [256, 1]
    const int*   nbr = (const int*)  d_in[3];   // [8192, 32]
    float* out = (float*)d_out;                 // [8192, 128]

    // ws: hWb bf16 (2 MB) | h1 (32 KB) | h2 (32 KB) | Wtf (64 KB) | wa1 | wa2
    unsigned short* hWb = (unsigned short*)d_ws;
    float* h1 = (float*)(hWb + (size_t)N_NODES * F_OUT);
    float* h2 = h1 + N_NODES;
    unsigned short* Wtf = (unsigned short*)(h2 + N_NODES);
    float* wa1 = (float*)(Wtf + (size_t)F_IN * F_OUT);
    float* wa2 = wa1 + F_IN;

    prep_kernel   <<<68, 64, 0, stream>>>(W, a, Wtf, wa1, wa2);
    gemm_mfma_v6  <<<N_NODES / 16, 256, 0, stream>>>(h, Wtf, wa1, wa2, hWb, h1, h2);
    attn_kernel_v8<<<N_NODES / 4,  256, 0, stream>>>(hWb, h1, h2, nbr, out);
}

// Round 9
// 85.113 us; speedup vs baseline: 2.9754x; 1.0016x over previous
//
#include <hip/hip_runtime.h>
#include <math.h>

#define N_NODES 8192
#define F_IN    256
#define F_OUT   128
#define DEG     32
#define ALPHA   0.2f

typedef __attribute__((ext_vector_type(8))) short short8;   // 8 bf16 = 4 VGPR
typedef __attribute__((ext_vector_type(4))) float floatx4;  // MFMA acc

__device__ __forceinline__ unsigned short f2bf(float x) {   // RNE f32->bf16
    unsigned u = __float_as_uint(x);
    return (unsigned short)((u + 0x7fffu + ((u >> 16) & 1u)) >> 16);
}

// packed f32x2 -> bf16x2 (RNE). Uses v_cvt_pk_bf16_f32 when available.
__device__ __forceinline__ unsigned pk_bf16(float lo, float hi) {
#if defined(__has_builtin) && __has_builtin(__builtin_amdgcn_cvt_pk_bf16_f32)
    typedef __attribute__((ext_vector_type(2))) __bf16 bf16x2;
    bf16x2 r = __builtin_amdgcn_cvt_pk_bf16_f32(lo, hi);
    return *(unsigned*)&r;
#else
    return (unsigned)f2bf(lo) | ((unsigned)f2bf(hi) << 16);
#endif
}

// ---- Kernel P: prep = pack W B-frags (blocks 0..63) + wa=W@a (blocks 64..67)
// B-frag layout (v5/v6-verified): frag f = kt*8 + gnt; lane holds
// B[k = kt*32 + quad*8 + j][n = gnt*16 + (lane&15)], j=0..7.
__global__ __launch_bounds__(64) void prep_kernel(
        const float* __restrict__ W, const float* __restrict__ a,
        unsigned short* __restrict__ Wtf,
        float* __restrict__ wa1, float* __restrict__ wa2) {
    const int bid = blockIdx.x;
    const int tid = threadIdx.x;
    if (bid < 64) {
        const int quad = tid >> 4;
        const int l15  = tid & 15;
        const int kt   = bid >> 3;
        const int gnt  = bid & 7;
        const int n    = gnt * 16 + l15;
        const int kb   = kt * 32 + quad * 8;
        float v[8];
        #pragma unroll
        for (int j = 0; j < 8; ++j)
            v[j] = W[(size_t)(kb + j) * F_OUT + n];
        uint4 p;
        p.x = pk_bf16(v[0], v[1]);
        p.y = pk_bf16(v[2], v[3]);
        p.z = pk_bf16(v[4], v[5]);
        p.w = pk_bf16(v[6], v[7]);
        ((uint4*)Wtf)[(size_t)bid * 64 + tid] = p;
    } else {
        const int k = (bid - 64) * 64 + tid;          // 0..255
        const float* wr = W + (size_t)k * F_OUT;
        float s1 = 0.f, s2 = 0.f;
        #pragma unroll 4
        for (int n = 0; n < F_OUT; n += 4) {
            float4 wv = *(const float4*)(wr + n);
            float4 a1 = *(const float4*)(a + n);
            float4 a2 = *(const float4*)(a + F_OUT + n);
            s1 = fmaf(wv.x,a1.x, fmaf(wv.y,a1.y, fmaf(wv.z,a1.z, fmaf(wv.w,a1.w, s1))));
            s2 = fmaf(wv.x,a2.x, fmaf(wv.y,a2.y, fmaf(wv.z,a2.z, fmaf(wv.w,a2.w, s2))));
        }
        wa1[k] = s1;
        wa2[k] = s2;
    }
}

// ---- Kernel A: hW(bf16) = h @ W via MFMA; h1/h2 from f32 h · (W@a) ----------
// 512 blocks x 256 thr. Block: 16 rows x 128 cols. Packed bf16 cvt for A-frags.
__global__ __launch_bounds__(256) void gemm_mfma_v9(
        const float* __restrict__ h,
        const unsigned short* __restrict__ Wtf,
        const float* __restrict__ wa1,
        const float* __restrict__ wa2,
        unsigned short* __restrict__ hWb,   // [8192][128] bf16
        float* __restrict__ h1,
        float* __restrict__ h2) {
    const int tid  = threadIdx.x;
    const int wave = tid >> 6;             // 0..3 = col quarter
    const int lane = tid & 63;
    const int quad = lane >> 4;
    const int l15  = lane & 15;
    const int row0 = blockIdx.x * 16;

    const float* hrow = h + (size_t)(row0 + l15) * F_IN + quad * 8;
    const short8* Wf  = (const short8*)Wtf;

    floatx4 acc[2] = {{0.f,0.f,0.f,0.f},{0.f,0.f,0.f,0.f}};
    float s1 = 0.f, s2 = 0.f;

    #pragma unroll
    for (int kt = 0; kt < 8; ++kt) {
        float4 v0 = *(const float4*)(hrow + kt * 32);
        float4 v1 = *(const float4*)(hrow + kt * 32 + 4);
        union { short8 s; uint4 u; } afu;
        afu.u.x = pk_bf16(v0.x, v0.y);
        afu.u.y = pk_bf16(v0.z, v0.w);
        afu.u.z = pk_bf16(v1.x, v1.y);
        afu.u.w = pk_bf16(v1.z, v1.w);
        short8 af = afu.s;

        #pragma unroll
        for (int nt = 0; nt < 2; ++nt) {
            short8 bf = Wf[(size_t)(kt * 8 + wave * 2 + nt) * 64 + lane];
            acc[nt] = __builtin_amdgcn_mfma_f32_16x16x32_bf16(af, bf, acc[nt], 0, 0, 0);
        }

        if (wave == 0) {                   // f32 score path: s += h · wa
            const int kb = kt * 32 + quad * 8;
            float4 u0 = *(const float4*)(wa1 + kb);
            float4 u1 = *(const float4*)(wa1 + kb + 4);
            float4 t0 = *(const float4*)(wa2 + kb);
            float4 t1 = *(const float4*)(wa2 + kb + 4);
            s1 = fmaf(v0.x,u0.x, fmaf(v0.y,u0.y, fmaf(v0.z,u0.z, fmaf(v0.w,u0.w, s1))));
            s1 = fmaf(v1.x,u1.x, fmaf(v1.y,u1.y, fmaf(v1.z,u1.z, fmaf(v1.w,u1.w, s1))));
            s2 = fmaf(v0.x,t0.x, fmaf(v0.y,t0.y, fmaf(v0.z,t0.z, fmaf(v0.w,t0.w, s2))));
            s2 = fmaf(v1.x,t1.x, fmaf(v1.y,t1.y, fmaf(v1.z,t1.z, fmaf(v1.w,t1.w, s2))));
        }
    }

    // store hW bf16: C/D layout col=lane&15, row=quad*4+reg
    #pragma unroll
    for (int nt = 0; nt < 2; ++nt) {
        const int col = wave * 32 + nt * 16 + l15;
        #pragma unroll
        for (int reg = 0; reg < 4; ++reg) {
            const int row = row0 + quad * 4 + reg;
            hWb[(size_t)row * F_OUT + col] = f2bf(acc[nt][reg]);
        }
    }

    if (wave == 0) {
        s1 += __shfl_xor(s1, 16); s1 += __shfl_xor(s1, 32);
        s2 += __shfl_xor(s2, 16); s2 += __shfl_xor(s2, 32);
        if (lane < 16) {
            h1[row0 + l15] = s1;
            h2[row0 + l15] = s2;
        }
    }
}

// ---- Kernel C v9: sparse softmax + branchless pipelined wide gather + ELU ---
// one wave per row. Gather: candidate q=it*4+grp, all shuffles hoisted, all 9
// uint4 loads issued branchless (invalid -> row self, weight 0) for full MLP.
__global__ __launch_bounds__(256) void attn_kernel_v9(
        const unsigned short* __restrict__ hWb,    // [8192][128] bf16
        const float* __restrict__ h1,
        const float* __restrict__ h2,
        const int*   __restrict__ nbr,
        float* __restrict__ out) {
    const int wave = threadIdx.x >> 6;
    const int lane = threadIdx.x & 63;
    const int row  = blockIdx.x * 4 + wave;
    const int grp  = lane >> 4;
    const int l15  = lane & 15;

    int col = -1;
    if (lane < DEG)       col = nbr[(size_t)row * DEG + lane];
    else if (lane == DEG) col = row;

    // dedup + multiplicity over the 33 candidate slots (scatter-add semantics)
    int cnt = 0;
    int firstq = lane;
    #pragma unroll
    for (int q = 0; q <= DEG; ++q) {
        int cq = __shfl(col, q);
        bool same = (cq == col);
        if (same && q < DEG)    cnt++;
        if (same && q < firstq) firstq = q;
    }
    const bool active = (lane <= DEG) && (col >= 0) && (firstq == lane);

    float mask_val = (float)cnt * (1.0f / 64.0f) + ((col == row) ? 0.5f : 0.0f);

    const float h1row = h1[row];
    float h2c = active ? h2[col] : 0.f;
    float s = mask_val * (h1row + h2c);
    float e = (s > 0.f) ? s : ALPHA * s;            // LeakyReLU
    bool valid = active && (e != 0.0f);             // e==0 -> NEG_INF in ref

    float ev = valid ? e : -INFINITY;
    #pragma unroll
    for (int off = 32; off > 0; off >>= 1)
        ev = fmaxf(ev, __shfl_xor(ev, off));
    float w = valid ? __expf(e - ev) : 0.f;
    float denom = w;
    #pragma unroll
    for (int off = 32; off > 0; off >>= 1)
        denom += __shfl_xor(denom, off);
    float att = w / denom;                          // exactly 0 for invalid lanes

    // ---- hoist all broadcast shuffles; branchless safe indices --------------
    float aq[9];
    const unsigned short* src[9];
    #pragma unroll
    for (int it = 0; it < 9; ++it) {
        const int q  = it * 4 + grp;                // 0..35 (<64, shfl-safe)
        float a_ = __shfl(att, q);                  // 0 for q>32 or invalid
        int   c_ = __shfl(col, q);
        bool ok = (a_ > 0.f);
        aq[it]  = ok ? a_ : 0.f;
        src[it] = hWb + (size_t)(ok ? c_ : row) * F_OUT;
    }

    // ---- 9 independent 16 B loads (full wave = 1 KiB each), then FMA --------
    uint4 p[9];
    #pragma unroll
    for (int it = 0; it < 9; ++it)
        p[it] = ((const uint4*)src[it])[l15];

    float acc[8] = {0.f,0.f,0.f,0.f,0.f,0.f,0.f,0.f};
    #pragma unroll
    for (int it = 0; it < 9; ++it) {
        const float a_ = aq[it];
        acc[0] = fmaf(a_, __uint_as_float(p[it].x << 16),         acc[0]);
        acc[1] = fmaf(a_, __uint_as_float(p[it].x & 0xffff0000u), acc[1]);
        acc[2] = fmaf(a_, __uint_as_float(p[it].y << 16),         acc[2]);
        acc[3] = fmaf(a_, __uint_as_float(p[it].y & 0xffff0000u), acc[3]);
        acc[4] = fmaf(a_, __uint_as_float(p[it].z << 16),         acc[4]);
        acc[5] = fmaf(a_, __uint_as_float(p[it].z & 0xffff0000u), acc[5]);
        acc[6] = fmaf(a_, __uint_as_float(p[it].w << 16),         acc[6]);
        acc[7] = fmaf(a_, __uint_as_float(p[it].w & 0xffff0000u), acc[7]);
    }

    // fold the 4 lane-groups
    #pragma unroll
    for (int j = 0; j < 8; ++j) {
        acc[j] += __shfl_xor(acc[j], 16);
        acc[j] += __shfl_xor(acc[j], 32);
    }

    if (grp == 0) {                                 // lanes 0..15 store 32 B each
        float4 o0, o1;
        o0.x = (acc[0] > 0.f) ? acc[0] : expm1f(acc[0]);
        o0.y = (acc[1] > 0.f) ? acc[1] : expm1f(acc[1]);
        o0.z = (acc[2] > 0.f) ? acc[2] : expm1f(acc[2]);
        o0.w = (acc[3] > 0.f) ? acc[3] : expm1f(acc[3]);
        o1.x = (acc[4] > 0.f) ? acc[4] : expm1f(acc[4]);
        o1.y = (acc[5] > 0.f) ? acc[5] : expm1f(acc[5]);
        o1.z = (acc[6] > 0.f) ? acc[6] : expm1f(acc[6]);
        o1.w = (acc[7] > 0.f) ? acc[7] : expm1f(acc[7]);
        float* orow = out + (size_t)row * F_OUT + l15 * 8;
        *(float4*)(orow)     = o0;
        *(float4*)(orow + 4) = o1;
    }
}

// -----------------------------------------------------------------------------
extern "C" void kernel_launch(void* const* d_in, const int* in_sizes, int n_in,
                              void* d_out, int out_size, void* d_ws, size_t ws_size,
                              hipStream_t stream) {
    const float* h   = (const float*)d_in[0];   // [8192, 256]
    const float* W   = (const float*)d_in[1];   // [256, 128]
    const float* a   = (const float*)d_in[2];   // [256, 1]
    const int*   nbr = (const int*)  d_in[3];   // [8192, 32]
    float* out = (float*)d_out;                 // [8192, 128]

    // ws: hWb bf16 (2 MB) | h1 (32 KB) | h2 (32 KB) | Wtf (64 KB) | wa1 | wa2
    unsigned short* hWb = (unsigned short*)d_ws;
    float* h1 = (float*)(hWb + (size_t)N_NODES * F_OUT);
    float* h2 = h1 + N_NODES;
    unsigned short* Wtf = (unsigned short*)(h2 + N_NODES);
    float* wa1 = (float*)(Wtf + (size_t)F_IN * F_OUT);
    float* wa2 = wa1 + F_IN;

    prep_kernel   <<<68, 64, 0, stream>>>(W, a, Wtf, wa1, wa2);
    gemm_mfma_v9  <<<N_NODES / 16, 256, 0, stream>>>(h, Wtf, wa1, wa2, hWb, h1, h2);
    attn_kernel_v9<<<N_NODES / 4,  256, 0, stream>>>(hWb, h1, h2, nbr, out);
}